// Round 3
// baseline (204.691 us; speedup 1.0000x reference)
//
#include <hip/hip_runtime.h>
#include <hip/hip_bf16.h>

// Problem constants
#define BB 2
#define TT 2048
#define DD 1024
#define NN 16
#define RR 64          // DT_RANK
#define MM (BB*TT)     // 4096 rows
#define KDIM DD        // 1024
#define CHUNK 32
#define NCHUNK (TT/CHUNK)  // 64
#define KSPLIT 8

// Workspace layout (in floats) — ~56 MB total
#define BT_OFF 0                      // Bt: MM*NN            = 65536 (pre-scaled by rA)
#define CT_OFF 65536                  // Ct: MM*NN            = 65536
#define R1_OFF 131072                 // R1: MM*RR            = 262144
#define DT_OFF 393216                 // (unused now; kept for layout stability)
#define P_OFF  4587520                // P : NCHUNK*BB*DD*NN  = 2097152
#define S_OFF  6684672                // S : same             = 2097152
#define H_OFF  8781824                // Hinit: same          = 2097152
#define PP_OFF 10878976               // Pp: KSPLIT*MM*96     = 3145728

#define LOG2E 1.4426950408889634f

#if __has_builtin(__builtin_amdgcn_exp2f)
#define EXP2(x) __builtin_amdgcn_exp2f(x)
#else
#define EXP2(x) exp2f(x)
#endif

__device__ __forceinline__ float softplus_f(float z) {
    return fmaxf(z, 0.0f) + log1pf(expf(-fabsf(z)));
}

// ---------------------------------------------------------------------------
// Kernel 1: combined projection partials  Pp[p] = x[:, p-slice] @ W^T
// cols = [B(16) | C(16) | dt1(64)].  (unchanged)
// ---------------------------------------------------------------------------
__global__ __launch_bounds__(256) void k_proj96(
    const float* __restrict__ x, const float* __restrict__ W_B,
    const float* __restrict__ W_C, const float* __restrict__ W_dt1,
    float* __restrict__ Pp)
{
    __shared__ float xs[16][68];
    __shared__ float wsT[16][97];

    const int tid = threadIdx.x;
    const int r0 = blockIdx.x * 64;
    const int kbase = blockIdx.y * (KDIM / KSPLIT);
    const int tx = tid & 15;
    const int ty = tid >> 4;

    float acc[4][6];
    #pragma unroll
    for (int i = 0; i < 4; i++)
        #pragma unroll
        for (int j = 0; j < 6; j++) acc[i][j] = 0.0f;

    for (int kc = 0; kc < KDIM / KSPLIT; kc += 16) {
        {
            const int row = tid >> 2;
            const int kq = (tid & 3) * 4;
            float4 v = *(const float4*)(x + (size_t)(r0 + row) * KDIM + kbase + kc + kq);
            xs[kq + 0][row] = v.x; xs[kq + 1][row] = v.y;
            xs[kq + 2][row] = v.z; xs[kq + 3][row] = v.w;
        }
        #pragma unroll
        for (int i = 0; i < 6; i++) {
            const int idx = i * 256 + tid;
            const int c = idx >> 4;
            const int kk = idx & 15;
            const float* wrow; int cc;
            if (c < 16)      { wrow = W_B;   cc = c; }
            else if (c < 32) { wrow = W_C;   cc = c - 16; }
            else             { wrow = W_dt1; cc = c - 32; }
            wsT[kk][c] = wrow[(size_t)cc * KDIM + kbase + kc + kk];
        }
        __syncthreads();
        #pragma unroll
        for (int kk = 0; kk < 16; kk++) {
            const float a0 = xs[kk][ty * 4 + 0];
            const float a1 = xs[kk][ty * 4 + 1];
            const float a2 = xs[kk][ty * 4 + 2];
            const float a3 = xs[kk][ty * 4 + 3];
            #pragma unroll
            for (int j = 0; j < 6; j++) {
                const float b = wsT[kk][tx + j * 16];
                acc[0][j] = fmaf(a0, b, acc[0][j]);
                acc[1][j] = fmaf(a1, b, acc[1][j]);
                acc[2][j] = fmaf(a2, b, acc[2][j]);
                acc[3][j] = fmaf(a3, b, acc[3][j]);
            }
        }
        __syncthreads();
    }

    float* out = Pp + (size_t)blockIdx.y * (MM * 96);
    #pragma unroll
    for (int i = 0; i < 4; i++) {
        const int r = r0 + ty * 4 + i;
        #pragma unroll
        for (int j = 0; j < 6; j++)
            out[(size_t)r * 96 + tx + j * 16] = acc[i][j];
    }
}

// ---------------------------------------------------------------------------
// Kernel 1b: sum the 8 k-split partials, scatter to Bt | Ct | R1. (unchanged)
// ---------------------------------------------------------------------------
__global__ __launch_bounds__(256) void k_reduce96(
    const float* __restrict__ Pp, const float* __restrict__ log_A,
    float* __restrict__ Bt, float* __restrict__ Ct, float* __restrict__ R1)
{
    const int gid = blockIdx.x * 256 + threadIdx.x;   // 0..98303
    const int e0 = gid * 4;
    float4 s = *(const float4*)(Pp + e0);
    #pragma unroll
    for (int p = 1; p < KSPLIT; p++) {
        const float4 v = *(const float4*)(Pp + (size_t)p * MM * 96 + e0);
        s.x += v.x; s.y += v.y; s.z += v.z; s.w += v.w;
    }
    const int r = e0 / 96;
    const int c = e0 - r * 96;
    if (c < 16) {
        const float4 lgj = *(const float4*)(log_A + c);
        s.x *= 1.0f / (-__expf(lgj.x) + 1e-8f);
        s.y *= 1.0f / (-__expf(lgj.y) + 1e-8f);
        s.z *= 1.0f / (-__expf(lgj.z) + 1e-8f);
        s.w *= 1.0f / (-__expf(lgj.w) + 1e-8f);
        *(float4*)(Bt + (size_t)r * NN + c) = s;
    } else if (c < 32) {
        *(float4*)(Ct + (size_t)r * NN + (c - 16)) = s;
    } else {
        *(float4*)(R1 + (size_t)r * RR + (c - 32)) = s;
    }
}

// ---------------------------------------------------------------------------
// Scan v10: dt-projection FUSED into the scans (k_dtproj eliminated).
// One thread per d-channel, 16 n-states in registers.  W_dt2 row d (64
// floats) lives in 16 float4 VGPRs, loaded once per block.  R1 chunk tile
// (32 t x 64 k, 8 KB) in LDS, read per-t as wave-uniform float4 broadcasts
// (conflict-free).  dt dot uses 4 partial accumulators (16-deep chains).
// ---------------------------------------------------------------------------
__global__ __launch_bounds__(256) void k_scan1(
    const float* __restrict__ x, const float* __restrict__ R1,
    const float* __restrict__ W_dt2, const float* __restrict__ b_dt2,
    const float* __restrict__ Bt, const float* __restrict__ log_A,
    float* __restrict__ P, float* __restrict__ Sg)
{
    __shared__ float bt_s[CHUNK][NN];    // 2 KB
    __shared__ float r1s[CHUNK][RR];     // 8 KB

    const int tid = threadIdx.x;
    const int d = blockIdx.x * 256 + tid;
    const int c = blockIdx.y;
    const int b = blockIdx.z;
    const int base = b * TT + c * CHUNK;

    // stage R1 tile: 32 rows x 64 k = 512 float4, 2 per thread (coalesced)
    #pragma unroll
    for (int i = 0; i < 2; i++) {
        const int f = tid + i * 256;
        const int row = f >> 4;
        const int kq = (f & 15) * 4;
        *(float4*)&r1s[row][kq] = *(const float4*)(R1 + (size_t)(base + row) * RR + kq);
    }
    if (tid < CHUNK * NN / 4) {          // 128 threads stage Bt
        const int t = tid >> 2;
        const int jc = (tid & 3) * 4;
        *(float4*)&bt_s[t][jc] = *(const float4*)(Bt + (size_t)(base + t) * NN + jc);
    }

    // W_dt2 row d -> registers (64 floats); bias
    float4 w4[16];
    #pragma unroll
    for (int q = 0; q < 16; q++)
        w4[q] = *(const float4*)(W_dt2 + (size_t)d * RR + q * 4);
    const float bias = b_dt2[d];

    float A2[16];
    #pragma unroll
    for (int q = 0; q < 4; q++) {
        const float4 lg = *(const float4*)(log_A + d * NN + q * 4);
        A2[q * 4 + 0] = -__expf(lg.x) * LOG2E;
        A2[q * 4 + 1] = -__expf(lg.y) * LOG2E;
        A2[q * 4 + 2] = -__expf(lg.z) * LOG2E;
        A2[q * 4 + 3] = -__expf(lg.w) * LOG2E;
    }

    const float* gx = x + (size_t)base * DD + d;

    __syncthreads();

    float s[16];
    #pragma unroll
    for (int n = 0; n < 16; n++) s[n] = 0.0f;
    float dtsum = 0.0f;

    #pragma unroll 2
    for (int t = 0; t < CHUNK; t++) {
        // dt[t][d] = softplus(dot(R1[t,:], W_dt2[d,:]) + bias)
        float pa0 = bias, pa1 = 0.f, pa2 = 0.f, pa3 = 0.f;
        #pragma unroll
        for (int q = 0; q < 16; q += 4) {
            const float4 r0v = *(const float4*)&r1s[t][(q + 0) * 4];
            const float4 r1v = *(const float4*)&r1s[t][(q + 1) * 4];
            const float4 r2v = *(const float4*)&r1s[t][(q + 2) * 4];
            const float4 r3v = *(const float4*)&r1s[t][(q + 3) * 4];
            pa0 = fmaf(r0v.x, w4[q + 0].x, pa0); pa0 = fmaf(r0v.y, w4[q + 0].y, pa0);
            pa0 = fmaf(r0v.z, w4[q + 0].z, pa0); pa0 = fmaf(r0v.w, w4[q + 0].w, pa0);
            pa1 = fmaf(r1v.x, w4[q + 1].x, pa1); pa1 = fmaf(r1v.y, w4[q + 1].y, pa1);
            pa1 = fmaf(r1v.z, w4[q + 1].z, pa1); pa1 = fmaf(r1v.w, w4[q + 1].w, pa1);
            pa2 = fmaf(r2v.x, w4[q + 2].x, pa2); pa2 = fmaf(r2v.y, w4[q + 2].y, pa2);
            pa2 = fmaf(r2v.z, w4[q + 2].z, pa2); pa2 = fmaf(r2v.w, w4[q + 2].w, pa2);
            pa3 = fmaf(r3v.x, w4[q + 3].x, pa3); pa3 = fmaf(r3v.y, w4[q + 3].y, pa3);
            pa3 = fmaf(r3v.z, w4[q + 3].z, pa3); pa3 = fmaf(r3v.w, w4[q + 3].w, pa3);
        }
        const float dtv = softplus_f((pa0 + pa1) + (pa2 + pa3));
        const float xv  = gx[(size_t)t * DD];
        dtsum += dtv;
        #pragma unroll
        for (int q = 0; q < 4; q++) {
            const float4 bt4 = *(const float4*)&bt_s[t][q * 4];
            const float a0 = EXP2(dtv * A2[q * 4 + 0]);
            const float a1 = EXP2(dtv * A2[q * 4 + 1]);
            const float a2 = EXP2(dtv * A2[q * 4 + 2]);
            const float a3 = EXP2(dtv * A2[q * 4 + 3]);
            const float u0 = xv * bt4.x;
            const float u1 = xv * bt4.y;
            const float u2 = xv * bt4.z;
            const float u3 = xv * bt4.w;
            s[q * 4 + 0] = fmaf(a0, s[q * 4 + 0] + u0, -u0);
            s[q * 4 + 1] = fmaf(a1, s[q * 4 + 1] + u1, -u1);
            s[q * 4 + 2] = fmaf(a2, s[q * 4 + 2] + u2, -u2);
            s[q * 4 + 3] = fmaf(a3, s[q * 4 + 3] + u3, -u3);
        }
    }

    const size_t o = ((size_t)(c * BB + b) * DD + d) * NN;
    #pragma unroll
    for (int q = 0; q < 4; q++) {
        *(float4*)(P + o + q * 4) = make_float4(
            EXP2(A2[q * 4 + 0] * dtsum), EXP2(A2[q * 4 + 1] * dtsum),
            EXP2(A2[q * 4 + 2] * dtsum), EXP2(A2[q * 4 + 3] * dtsum));
        *(float4*)(Sg + o + q * 4) = make_float4(
            s[q * 4 + 0], s[q * 4 + 1], s[q * 4 + 2], s[q * 4 + 3]);
    }
}

// Prefix-combine over chunks: Hinit[c] = h-state at START of chunk c. (unchanged)
__global__ __launch_bounds__(256) void k_comb(
    const float* __restrict__ P, const float* __restrict__ Sg,
    float* __restrict__ Hs)
{
    const int flat = blockIdx.x * 256 + threadIdx.x;   // 0..32767
    float h = 0.0f;
    #pragma unroll 8
    for (int c = 0; c < NCHUNK; c++) {
        const size_t idx = (size_t)c * (BB * DD * NN) + flat;
        Hs[idx] = h;
        h = fmaf(P[idx], h, Sg[idx]);
    }
}

__global__ __launch_bounds__(256) void k_scan2(
    const float* __restrict__ x, const float* __restrict__ R1,
    const float* __restrict__ W_dt2, const float* __restrict__ b_dt2,
    const float* __restrict__ Bt, const float* __restrict__ Ct,
    const float* __restrict__ log_A, const float* __restrict__ D_skip,
    const float* __restrict__ Hs, float* __restrict__ y)
{
    __shared__ float bt_s[CHUNK][NN];    // 2 KB
    __shared__ float ct_s[CHUNK][NN];    // 2 KB
    __shared__ float r1s[CHUNK][RR];     // 8 KB

    const int tid = threadIdx.x;
    const int d = blockIdx.x * 256 + tid;
    const int c = blockIdx.y;
    const int b = blockIdx.z;
    const int base = b * TT + c * CHUNK;

    #pragma unroll
    for (int i = 0; i < 2; i++) {
        const int f = tid + i * 256;
        const int row = f >> 4;
        const int kq = (f & 15) * 4;
        *(float4*)&r1s[row][kq] = *(const float4*)(R1 + (size_t)(base + row) * RR + kq);
    }
    if (tid < 128) {                     // 128 threads Bt, 128 Ct
        const int t = tid >> 2;
        const int jc = (tid & 3) * 4;
        *(float4*)&bt_s[t][jc] = *(const float4*)(Bt + (size_t)(base + t) * NN + jc);
    } else {
        const int t2 = (tid - 128) >> 2;
        const int jc = (tid & 3) * 4;
        *(float4*)&ct_s[t2][jc] = *(const float4*)(Ct + (size_t)(base + t2) * NN + jc);
    }

    float4 w4[16];
    #pragma unroll
    for (int q = 0; q < 16; q++)
        w4[q] = *(const float4*)(W_dt2 + (size_t)d * RR + q * 4);
    const float bias = b_dt2[d];

    float A2[16];
    #pragma unroll
    for (int q = 0; q < 4; q++) {
        const float4 lg = *(const float4*)(log_A + d * NN + q * 4);
        A2[q * 4 + 0] = -__expf(lg.x) * LOG2E;
        A2[q * 4 + 1] = -__expf(lg.y) * LOG2E;
        A2[q * 4 + 2] = -__expf(lg.z) * LOG2E;
        A2[q * 4 + 3] = -__expf(lg.w) * LOG2E;
    }
    const float dsk = D_skip[d];

    float h[16];
    {
        const size_t hoff = (size_t)c * (BB * DD * NN) + (size_t)b * (DD * NN) + (size_t)d * NN;
        #pragma unroll
        for (int q = 0; q < 4; q++) {
            const float4 hv = *(const float4*)(Hs + hoff + q * 4);
            h[q * 4 + 0] = hv.x; h[q * 4 + 1] = hv.y;
            h[q * 4 + 2] = hv.z; h[q * 4 + 3] = hv.w;
        }
    }

    const float* gx = x + (size_t)base * DD + d;

    __syncthreads();

    float* yp = y + (size_t)base * DD + d;

    #pragma unroll 2
    for (int t = 0; t < CHUNK; t++) {
        float pa0 = bias, pa1 = 0.f, pa2 = 0.f, pa3 = 0.f;
        #pragma unroll
        for (int q = 0; q < 16; q += 4) {
            const float4 r0v = *(const float4*)&r1s[t][(q + 0) * 4];
            const float4 r1v = *(const float4*)&r1s[t][(q + 1) * 4];
            const float4 r2v = *(const float4*)&r1s[t][(q + 2) * 4];
            const float4 r3v = *(const float4*)&r1s[t][(q + 3) * 4];
            pa0 = fmaf(r0v.x, w4[q + 0].x, pa0); pa0 = fmaf(r0v.y, w4[q + 0].y, pa0);
            pa0 = fmaf(r0v.z, w4[q + 0].z, pa0); pa0 = fmaf(r0v.w, w4[q + 0].w, pa0);
            pa1 = fmaf(r1v.x, w4[q + 1].x, pa1); pa1 = fmaf(r1v.y, w4[q + 1].y, pa1);
            pa1 = fmaf(r1v.z, w4[q + 1].z, pa1); pa1 = fmaf(r1v.w, w4[q + 1].w, pa1);
            pa2 = fmaf(r2v.x, w4[q + 2].x, pa2); pa2 = fmaf(r2v.y, w4[q + 2].y, pa2);
            pa2 = fmaf(r2v.z, w4[q + 2].z, pa2); pa2 = fmaf(r2v.w, w4[q + 2].w, pa2);
            pa3 = fmaf(r3v.x, w4[q + 3].x, pa3); pa3 = fmaf(r3v.y, w4[q + 3].y, pa3);
            pa3 = fmaf(r3v.z, w4[q + 3].z, pa3); pa3 = fmaf(r3v.w, w4[q + 3].w, pa3);
        }
        const float dtv = softplus_f((pa0 + pa1) + (pa2 + pa3));
        const float xv  = gx[(size_t)t * DD];
        float part = 0.0f;
        #pragma unroll
        for (int q = 0; q < 4; q++) {
            const float4 bt4 = *(const float4*)&bt_s[t][q * 4];
            const float4 ct4 = *(const float4*)&ct_s[t][q * 4];
            const float a0 = EXP2(dtv * A2[q * 4 + 0]);
            const float a1 = EXP2(dtv * A2[q * 4 + 1]);
            const float a2 = EXP2(dtv * A2[q * 4 + 2]);
            const float a3 = EXP2(dtv * A2[q * 4 + 3]);
            const float u0 = xv * bt4.x;
            const float u1 = xv * bt4.y;
            const float u2 = xv * bt4.z;
            const float u3 = xv * bt4.w;
            h[q * 4 + 0] = fmaf(a0, h[q * 4 + 0] + u0, -u0);
            h[q * 4 + 1] = fmaf(a1, h[q * 4 + 1] + u1, -u1);
            h[q * 4 + 2] = fmaf(a2, h[q * 4 + 2] + u2, -u2);
            h[q * 4 + 3] = fmaf(a3, h[q * 4 + 3] + u3, -u3);
            part = fmaf(h[q * 4 + 0], ct4.x, part);
            part = fmaf(h[q * 4 + 1], ct4.y, part);
            part = fmaf(h[q * 4 + 2], ct4.z, part);
            part = fmaf(h[q * 4 + 3], ct4.w, part);
        }
        yp[(size_t)t * DD] = fmaf(dsk, xv, part);
    }
}

// ---------------------------------------------------------------------------
extern "C" void kernel_launch(void* const* d_in, const int* in_sizes, int n_in,
                              void* d_out, int out_size, void* d_ws, size_t ws_size,
                              hipStream_t stream)
{
    const float* x      = (const float*)d_in[0];
    const float* W_B    = (const float*)d_in[1];
    const float* W_C    = (const float*)d_in[2];
    const float* W_dt1  = (const float*)d_in[3];
    const float* W_dt2  = (const float*)d_in[4];
    const float* b_dt2  = (const float*)d_in[5];
    const float* log_A  = (const float*)d_in[6];
    const float* D_skip = (const float*)d_in[7];
    float* y = (float*)d_out;

    float* ws = (float*)d_ws;
    float* Bt = ws + BT_OFF;
    float* Ct = ws + CT_OFF;
    float* R1 = ws + R1_OFF;
    float* P  = ws + P_OFF;
    float* S  = ws + S_OFF;
    float* Hs = ws + H_OFF;
    float* Pp = ws + PP_OFF;

    k_proj96<<<dim3(MM / 64, KSPLIT), 256, 0, stream>>>(x, W_B, W_C, W_dt1, Pp);
    k_reduce96<<<dim3(MM * 96 / 4 / 256), 256, 0, stream>>>(Pp, log_A, Bt, Ct, R1);
    k_scan1<<<dim3(DD / 256, NCHUNK, BB), 256, 0, stream>>>(x, R1, W_dt2, b_dt2, Bt, log_A, P, S);
    k_comb<<<dim3(BB * DD * NN / 256), 256, 0, stream>>>(P, S, Hs);
    k_scan2<<<dim3(DD / 256, NCHUNK, BB), 256, 0, stream>>>(x, R1, W_dt2, b_dt2, Bt, Ct, log_A, D_skip, Hs, y);
}

// Round 4
// 167.255 us; speedup vs baseline: 1.2238x; 1.2238x over previous
//
#include <hip/hip_runtime.h>
#include <hip/hip_bf16.h>

// Problem constants
#define BB 2
#define TT 2048
#define DD 1024
#define NN 16
#define RR 64          // DT_RANK
#define MM (BB*TT)     // 4096 rows
#define KDIM DD        // 1024
#define CHUNK 32
#define NCHUNK (TT/CHUNK)  // 64
#define KSPLIT 8

// Workspace layout (in floats) — ~56 MB total
#define BT_OFF 0                      // Bt: MM*NN            = 65536 (pre-scaled by rA)
#define CT_OFF 65536                  // Ct: MM*NN            = 65536
#define R1_OFF 131072                 // R1: MM*RR            = 262144
#define DT_OFF 393216                 // dt: MM*DD            = 4194304
#define P_OFF  4587520                // P : NCHUNK*BB*DD*NN  = 2097152
#define S_OFF  6684672                // S : same             = 2097152
#define H_OFF  8781824                // Hinit: same          = 2097152
#define PP_OFF 10878976               // Pp: KSPLIT*MM*96     = 3145728

#define LOG2E 1.4426950408889634f

#if __has_builtin(__builtin_amdgcn_exp2f)
#define EXP2(x) __builtin_amdgcn_exp2f(x)
#else
#define EXP2(x) exp2f(x)
#endif

__device__ __forceinline__ float softplus_f(float z) {
    return fmaxf(z, 0.0f) + log1pf(expf(-fabsf(z)));
}

// ---------------------------------------------------------------------------
// Kernel 1: combined projection partials  Pp[p] = x[:, p-slice] @ W^T
// cols = [B(16) | C(16) | dt1(64)].  (unchanged)
// ---------------------------------------------------------------------------
__global__ __launch_bounds__(256) void k_proj96(
    const float* __restrict__ x, const float* __restrict__ W_B,
    const float* __restrict__ W_C, const float* __restrict__ W_dt1,
    float* __restrict__ Pp)
{
    __shared__ float xs[16][68];
    __shared__ float wsT[16][97];

    const int tid = threadIdx.x;
    const int r0 = blockIdx.x * 64;
    const int kbase = blockIdx.y * (KDIM / KSPLIT);
    const int tx = tid & 15;
    const int ty = tid >> 4;

    float acc[4][6];
    #pragma unroll
    for (int i = 0; i < 4; i++)
        #pragma unroll
        for (int j = 0; j < 6; j++) acc[i][j] = 0.0f;

    for (int kc = 0; kc < KDIM / KSPLIT; kc += 16) {
        {
            const int row = tid >> 2;
            const int kq = (tid & 3) * 4;
            float4 v = *(const float4*)(x + (size_t)(r0 + row) * KDIM + kbase + kc + kq);
            xs[kq + 0][row] = v.x; xs[kq + 1][row] = v.y;
            xs[kq + 2][row] = v.z; xs[kq + 3][row] = v.w;
        }
        #pragma unroll
        for (int i = 0; i < 6; i++) {
            const int idx = i * 256 + tid;
            const int c = idx >> 4;
            const int kk = idx & 15;
            const float* wrow; int cc;
            if (c < 16)      { wrow = W_B;   cc = c; }
            else if (c < 32) { wrow = W_C;   cc = c - 16; }
            else             { wrow = W_dt1; cc = c - 32; }
            wsT[kk][c] = wrow[(size_t)cc * KDIM + kbase + kc + kk];
        }
        __syncthreads();
        #pragma unroll
        for (int kk = 0; kk < 16; kk++) {
            const float a0 = xs[kk][ty * 4 + 0];
            const float a1 = xs[kk][ty * 4 + 1];
            const float a2 = xs[kk][ty * 4 + 2];
            const float a3 = xs[kk][ty * 4 + 3];
            #pragma unroll
            for (int j = 0; j < 6; j++) {
                const float b = wsT[kk][tx + j * 16];
                acc[0][j] = fmaf(a0, b, acc[0][j]);
                acc[1][j] = fmaf(a1, b, acc[1][j]);
                acc[2][j] = fmaf(a2, b, acc[2][j]);
                acc[3][j] = fmaf(a3, b, acc[3][j]);
            }
        }
        __syncthreads();
    }

    float* out = Pp + (size_t)blockIdx.y * (MM * 96);
    #pragma unroll
    for (int i = 0; i < 4; i++) {
        const int r = r0 + ty * 4 + i;
        #pragma unroll
        for (int j = 0; j < 6; j++)
            out[(size_t)r * 96 + tx + j * 16] = acc[i][j];
    }
}

// ---------------------------------------------------------------------------
// Kernel 1b: sum the 8 k-split partials, scatter to Bt | Ct | R1. (unchanged)
// ---------------------------------------------------------------------------
__global__ __launch_bounds__(256) void k_reduce96(
    const float* __restrict__ Pp, const float* __restrict__ log_A,
    float* __restrict__ Bt, float* __restrict__ Ct, float* __restrict__ R1)
{
    const int gid = blockIdx.x * 256 + threadIdx.x;   // 0..98303
    const int e0 = gid * 4;
    float4 s = *(const float4*)(Pp + e0);
    #pragma unroll
    for (int p = 1; p < KSPLIT; p++) {
        const float4 v = *(const float4*)(Pp + (size_t)p * MM * 96 + e0);
        s.x += v.x; s.y += v.y; s.z += v.z; s.w += v.w;
    }
    const int r = e0 / 96;
    const int c = e0 - r * 96;
    if (c < 16) {
        const float4 lgj = *(const float4*)(log_A + c);
        s.x *= 1.0f / (-__expf(lgj.x) + 1e-8f);
        s.y *= 1.0f / (-__expf(lgj.y) + 1e-8f);
        s.z *= 1.0f / (-__expf(lgj.z) + 1e-8f);
        s.w *= 1.0f / (-__expf(lgj.w) + 1e-8f);
        *(float4*)(Bt + (size_t)r * NN + c) = s;
    } else if (c < 32) {
        *(float4*)(Ct + (size_t)r * NN + (c - 16)) = s;
    } else {
        *(float4*)(R1 + (size_t)r * RR + (c - 32)) = s;
    }
}

// ---------------------------------------------------------------------------
// Kernel 2 v2: dt = softplus(R1 @ W_dt2^T + b_dt2).
// 64x64 tile, K=64 single pass.  Grid (64,16)=1024 blocks -> 4 blocks/CU,
// LDS 34.6 KB, __launch_bounds__(256,4) -> 16 waves/CU (2x the old version's
// latency hiding with 1/3 the LDS).  Padded tiles (stride 68) keep both the
// broadcast r1 reads and the w float4 reads conflict-light.
// ---------------------------------------------------------------------------
__global__ __launch_bounds__(256, 4) void k_dtproj(
    const float* __restrict__ R1, const float* __restrict__ W_dt2,
    const float* __restrict__ b_dt2, float* __restrict__ dt)
{
    __shared__ float r1s[64][68];    // 17.4 KB
    __shared__ float wsT[64][68];    // 17.4 KB  (wsT[k][d])

    const int tid = threadIdx.x;
    const int r0 = blockIdx.x * 64;
    const int d0 = blockIdx.y * 64;

    // stage R1 tile: 64 rows x 64 k = 1024 float4, 4 per thread (coalesced)
    #pragma unroll
    for (int i = 0; i < 4; i++) {
        const int f = tid + i * 256;
        const int row = f >> 4;
        const int kq = (f & 15) * 4;
        *(float4*)&r1s[row][kq] = *(const float4*)(R1 + (size_t)(r0 + row) * RR + kq);
    }
    // stage W_dt2 tile transposed: thread (dl = tid>>2) reads 16 consecutive k
    // of row d0+dl, scatters to wsT[k][dl].
    {
        const int dl = tid >> 2;
        const int kq0 = (tid & 3) * 16;
        const float* src = W_dt2 + (size_t)(d0 + dl) * RR + kq0;
        #pragma unroll
        for (int j = 0; j < 16; j += 4) {
            const float4 v = *(const float4*)(src + j);
            wsT[kq0 + j + 0][dl] = v.x;
            wsT[kq0 + j + 1][dl] = v.y;
            wsT[kq0 + j + 2][dl] = v.z;
            wsT[kq0 + j + 3][dl] = v.w;
        }
    }
    __syncthreads();

    const int cg = tid & 15;   // cols d0 + cg*4 .. +3
    const int rg = tid >> 4;   // rows r0 + rg*4 + i

    float4 acc[4];
    #pragma unroll
    for (int i = 0; i < 4; i++) acc[i] = make_float4(0.f, 0.f, 0.f, 0.f);

    #pragma unroll
    for (int k4 = 0; k4 < 16; k4++) {
        float r1a[4][4];
        #pragma unroll
        for (int i = 0; i < 4; i++) {
            const float4 v = *(const float4*)&r1s[rg * 4 + i][k4 * 4];
            r1a[i][0] = v.x; r1a[i][1] = v.y; r1a[i][2] = v.z; r1a[i][3] = v.w;
        }
        #pragma unroll
        for (int kk = 0; kk < 4; kk++) {
            const float4 w = *(const float4*)&wsT[k4 * 4 + kk][cg * 4];
            #pragma unroll
            for (int i = 0; i < 4; i++) {
                const float a = r1a[i][kk];
                acc[i].x = fmaf(a, w.x, acc[i].x);
                acc[i].y = fmaf(a, w.y, acc[i].y);
                acc[i].z = fmaf(a, w.z, acc[i].z);
                acc[i].w = fmaf(a, w.w, acc[i].w);
            }
        }
    }

    const float4 bias = *(const float4*)(b_dt2 + d0 + cg * 4);
    #pragma unroll
    for (int i = 0; i < 4; i++) {
        const int row = r0 + rg * 4 + i;
        float4 o;
        o.x = softplus_f(acc[i].x + bias.x);
        o.y = softplus_f(acc[i].y + bias.y);
        o.z = softplus_f(acc[i].z + bias.z);
        o.w = softplus_f(acc[i].w + bias.w);
        *(float4*)(dt + (size_t)row * DD + d0 + cg * 4) = o;
    }
}

// ---------------------------------------------------------------------------
// Scan v9 (round-2, known-good): ONE THREAD PER d-CHANNEL, 16 n-states in
// registers.  Per t-step: 2 coalesced scalar global loads (x, dt) against
// ~100 VALU instrs.  Bt/Ct in LDS as wave-uniform broadcasts.  Chunk prefix
// states precomputed by k_comb.
// ---------------------------------------------------------------------------
__global__ __launch_bounds__(256, 2) void k_scan1(
    const float* __restrict__ x, const float* __restrict__ dt,
    const float* __restrict__ Bt, const float* __restrict__ log_A,
    float* __restrict__ P, float* __restrict__ Sg)
{
    __shared__ float bt_s[CHUNK][NN];   // 2 KB

    const int tid = threadIdx.x;
    const int d = blockIdx.x * 256 + tid;
    const int c = blockIdx.y;
    const int b = blockIdx.z;
    const int base = b * TT + c * CHUNK;

    if (tid < CHUNK * NN / 4) {         // 128 threads stage Bt
        const int t = tid >> 2;
        const int jc = (tid & 3) * 4;
        *(float4*)&bt_s[t][jc] = *(const float4*)(Bt + (size_t)(base + t) * NN + jc);
    }

    float A2[16];
    #pragma unroll
    for (int q = 0; q < 4; q++) {
        const float4 lg = *(const float4*)(log_A + d * NN + q * 4);
        A2[q * 4 + 0] = -__expf(lg.x) * LOG2E;
        A2[q * 4 + 1] = -__expf(lg.y) * LOG2E;
        A2[q * 4 + 2] = -__expf(lg.z) * LOG2E;
        A2[q * 4 + 3] = -__expf(lg.w) * LOG2E;
    }

    const float* gdt = dt + (size_t)base * DD + d;
    const float* gx  = x  + (size_t)base * DD + d;

    __syncthreads();

    float s[16];
    #pragma unroll
    for (int n = 0; n < 16; n++) s[n] = 0.0f;
    float dtsum = 0.0f;

    #pragma unroll 4
    for (int t = 0; t < CHUNK; t++) {
        const float dtv = gdt[(size_t)t * DD];
        const float xv  = gx[(size_t)t * DD];
        dtsum += dtv;
        #pragma unroll
        for (int q = 0; q < 4; q++) {
            const float4 bt4 = *(const float4*)&bt_s[t][q * 4];
            const float a0 = EXP2(dtv * A2[q * 4 + 0]);
            const float a1 = EXP2(dtv * A2[q * 4 + 1]);
            const float a2 = EXP2(dtv * A2[q * 4 + 2]);
            const float a3 = EXP2(dtv * A2[q * 4 + 3]);
            const float u0 = xv * bt4.x;
            const float u1 = xv * bt4.y;
            const float u2 = xv * bt4.z;
            const float u3 = xv * bt4.w;
            s[q * 4 + 0] = fmaf(a0, s[q * 4 + 0] + u0, -u0);
            s[q * 4 + 1] = fmaf(a1, s[q * 4 + 1] + u1, -u1);
            s[q * 4 + 2] = fmaf(a2, s[q * 4 + 2] + u2, -u2);
            s[q * 4 + 3] = fmaf(a3, s[q * 4 + 3] + u3, -u3);
        }
    }

    const size_t o = ((size_t)(c * BB + b) * DD + d) * NN;
    #pragma unroll
    for (int q = 0; q < 4; q++) {
        *(float4*)(P + o + q * 4) = make_float4(
            EXP2(A2[q * 4 + 0] * dtsum), EXP2(A2[q * 4 + 1] * dtsum),
            EXP2(A2[q * 4 + 2] * dtsum), EXP2(A2[q * 4 + 3] * dtsum));
        *(float4*)(Sg + o + q * 4) = make_float4(
            s[q * 4 + 0], s[q * 4 + 1], s[q * 4 + 2], s[q * 4 + 3]);
    }
}

// Prefix-combine over chunks: Hinit[c] = h-state at START of chunk c. (unchanged)
__global__ __launch_bounds__(256) void k_comb(
    const float* __restrict__ P, const float* __restrict__ Sg,
    float* __restrict__ Hs)
{
    const int flat = blockIdx.x * 256 + threadIdx.x;   // 0..32767
    float h = 0.0f;
    #pragma unroll 8
    for (int c = 0; c < NCHUNK; c++) {
        const size_t idx = (size_t)c * (BB * DD * NN) + flat;
        Hs[idx] = h;
        h = fmaf(P[idx], h, Sg[idx]);
    }
}

__global__ __launch_bounds__(256, 2) void k_scan2(
    const float* __restrict__ x, const float* __restrict__ dt,
    const float* __restrict__ Bt, const float* __restrict__ Ct,
    const float* __restrict__ log_A, const float* __restrict__ D_skip,
    const float* __restrict__ Hs, float* __restrict__ y)
{
    __shared__ float bt_s[CHUNK][NN];   // 2 KB
    __shared__ float ct_s[CHUNK][NN];   // 2 KB

    const int tid = threadIdx.x;
    const int d = blockIdx.x * 256 + tid;
    const int c = blockIdx.y;
    const int b = blockIdx.z;
    const int base = b * TT + c * CHUNK;

    if (tid < 128) {                    // 128 threads stage Bt, 128 Ct
        const int t = tid >> 2;
        const int jc = (tid & 3) * 4;
        *(float4*)&bt_s[t][jc] = *(const float4*)(Bt + (size_t)(base + t) * NN + jc);
    } else {
        const int t2 = (tid - 128) >> 2;
        const int jc = (tid & 3) * 4;
        *(float4*)&ct_s[t2][jc] = *(const float4*)(Ct + (size_t)(base + t2) * NN + jc);
    }

    float A2[16];
    #pragma unroll
    for (int q = 0; q < 4; q++) {
        const float4 lg = *(const float4*)(log_A + d * NN + q * 4);
        A2[q * 4 + 0] = -__expf(lg.x) * LOG2E;
        A2[q * 4 + 1] = -__expf(lg.y) * LOG2E;
        A2[q * 4 + 2] = -__expf(lg.z) * LOG2E;
        A2[q * 4 + 3] = -__expf(lg.w) * LOG2E;
    }
    const float dsk = D_skip[d];

    float h[16];
    {
        const size_t hoff = (size_t)c * (BB * DD * NN) + (size_t)b * (DD * NN) + (size_t)d * NN;
        #pragma unroll
        for (int q = 0; q < 4; q++) {
            const float4 hv = *(const float4*)(Hs + hoff + q * 4);
            h[q * 4 + 0] = hv.x; h[q * 4 + 1] = hv.y;
            h[q * 4 + 2] = hv.z; h[q * 4 + 3] = hv.w;
        }
    }

    const float* gdt = dt + (size_t)base * DD + d;
    const float* gx  = x  + (size_t)base * DD + d;

    __syncthreads();

    float* yp = y + (size_t)base * DD + d;

    #pragma unroll 4
    for (int t = 0; t < CHUNK; t++) {
        const float dtv = gdt[(size_t)t * DD];
        const float xv  = gx[(size_t)t * DD];
        float part = 0.0f;
        #pragma unroll
        for (int q = 0; q < 4; q++) {
            const float4 bt4 = *(const float4*)&bt_s[t][q * 4];
            const float4 ct4 = *(const float4*)&ct_s[t][q * 4];
            const float a0 = EXP2(dtv * A2[q * 4 + 0]);
            const float a1 = EXP2(dtv * A2[q * 4 + 1]);
            const float a2 = EXP2(dtv * A2[q * 4 + 2]);
            const float a3 = EXP2(dtv * A2[q * 4 + 3]);
            const float u0 = xv * bt4.x;
            const float u1 = xv * bt4.y;
            const float u2 = xv * bt4.z;
            const float u3 = xv * bt4.w;
            h[q * 4 + 0] = fmaf(a0, h[q * 4 + 0] + u0, -u0);
            h[q * 4 + 1] = fmaf(a1, h[q * 4 + 1] + u1, -u1);
            h[q * 4 + 2] = fmaf(a2, h[q * 4 + 2] + u2, -u2);
            h[q * 4 + 3] = fmaf(a3, h[q * 4 + 3] + u3, -u3);
            part = fmaf(h[q * 4 + 0], ct4.x, part);
            part = fmaf(h[q * 4 + 1], ct4.y, part);
            part = fmaf(h[q * 4 + 2], ct4.z, part);
            part = fmaf(h[q * 4 + 3], ct4.w, part);
        }
        yp[(size_t)t * DD] = fmaf(dsk, xv, part);
    }
}

// ---------------------------------------------------------------------------
extern "C" void kernel_launch(void* const* d_in, const int* in_sizes, int n_in,
                              void* d_out, int out_size, void* d_ws, size_t ws_size,
                              hipStream_t stream)
{
    const float* x      = (const float*)d_in[0];
    const float* W_B    = (const float*)d_in[1];
    const float* W_C    = (const float*)d_in[2];
    const float* W_dt1  = (const float*)d_in[3];
    const float* W_dt2  = (const float*)d_in[4];
    const float* b_dt2  = (const float*)d_in[5];
    const float* log_A  = (const float*)d_in[6];
    const float* D_skip = (const float*)d_in[7];
    float* y = (float*)d_out;

    float* ws = (float*)d_ws;
    float* Bt = ws + BT_OFF;
    float* Ct = ws + CT_OFF;
    float* R1 = ws + R1_OFF;
    float* dt = ws + DT_OFF;
    float* P  = ws + P_OFF;
    float* S  = ws + S_OFF;
    float* Hs = ws + H_OFF;
    float* Pp = ws + PP_OFF;

    k_proj96<<<dim3(MM / 64, KSPLIT), 256, 0, stream>>>(x, W_B, W_C, W_dt1, Pp);
    k_reduce96<<<dim3(MM * 96 / 4 / 256), 256, 0, stream>>>(Pp, log_A, Bt, Ct, R1);
    k_dtproj<<<dim3(MM / 64, DD / 64), 256, 0, stream>>>(R1, W_dt2, b_dt2, dt);
    k_scan1<<<dim3(DD / 256, NCHUNK, BB), 256, 0, stream>>>(x, dt, Bt, log_A, P, S);
    k_comb<<<dim3(BB * DD * NN / 256), 256, 0, stream>>>(P, S, Hs);
    k_scan2<<<dim3(DD / 256, NCHUNK, BB), 256, 0, stream>>>(x, dt, Bt, Ct, log_A, D_skip, Hs, y);
}

// Round 5
// 162.406 us; speedup vs baseline: 1.2604x; 1.0299x over previous
//
#include <hip/hip_runtime.h>
#include <hip/hip_bf16.h>

// Problem constants
#define BB 2
#define TT 2048
#define DD 1024
#define NN 16
#define RR 64          // DT_RANK
#define MM (BB*TT)     // 4096 rows
#define KDIM DD        // 1024
#define CHUNK 32
#define NCHUNK (TT/CHUNK)  // 64
#define KSPLIT 8

// Workspace layout (in floats) — ~56 MB total
#define BT_OFF 0                      // Bt: MM*NN            = 65536 (pre-scaled by rA)
#define CT_OFF 65536                  // Ct: MM*NN            = 65536
#define R1_OFF 131072                 // R1: MM*RR            = 262144
#define DT_OFF 393216                 // dt: MM*DD            = 4194304
#define P_OFF  4587520                // P : NCHUNK*BB*DD*NN  = 2097152
#define S_OFF  6684672                // S : same             = 2097152
#define H_OFF  8781824                // Hinit: same          = 2097152
#define PP_OFF 10878976               // Pp: KSPLIT*MM*96     = 3145728

#define LOG2E 1.4426950408889634f

#if __has_builtin(__builtin_amdgcn_exp2f)
#define EXP2(x) __builtin_amdgcn_exp2f(x)
#else
#define EXP2(x) exp2f(x)
#endif

__device__ __forceinline__ float softplus_f(float z) {
    return fmaxf(z, 0.0f) + log1pf(expf(-fabsf(z)));
}

// ---------------------------------------------------------------------------
// Kernel 1: combined projection partials  Pp[p] = x[:, p-slice] @ W^T
// cols = [B(16) | C(16) | dt1(64)].  (unchanged)
// ---------------------------------------------------------------------------
__global__ __launch_bounds__(256) void k_proj96(
    const float* __restrict__ x, const float* __restrict__ W_B,
    const float* __restrict__ W_C, const float* __restrict__ W_dt1,
    float* __restrict__ Pp)
{
    __shared__ float xs[16][68];
    __shared__ float wsT[16][97];

    const int tid = threadIdx.x;
    const int r0 = blockIdx.x * 64;
    const int kbase = blockIdx.y * (KDIM / KSPLIT);
    const int tx = tid & 15;
    const int ty = tid >> 4;

    float acc[4][6];
    #pragma unroll
    for (int i = 0; i < 4; i++)
        #pragma unroll
        for (int j = 0; j < 6; j++) acc[i][j] = 0.0f;

    for (int kc = 0; kc < KDIM / KSPLIT; kc += 16) {
        {
            const int row = tid >> 2;
            const int kq = (tid & 3) * 4;
            float4 v = *(const float4*)(x + (size_t)(r0 + row) * KDIM + kbase + kc + kq);
            xs[kq + 0][row] = v.x; xs[kq + 1][row] = v.y;
            xs[kq + 2][row] = v.z; xs[kq + 3][row] = v.w;
        }
        #pragma unroll
        for (int i = 0; i < 6; i++) {
            const int idx = i * 256 + tid;
            const int c = idx >> 4;
            const int kk = idx & 15;
            const float* wrow; int cc;
            if (c < 16)      { wrow = W_B;   cc = c; }
            else if (c < 32) { wrow = W_C;   cc = c - 16; }
            else             { wrow = W_dt1; cc = c - 32; }
            wsT[kk][c] = wrow[(size_t)cc * KDIM + kbase + kc + kk];
        }
        __syncthreads();
        #pragma unroll
        for (int kk = 0; kk < 16; kk++) {
            const float a0 = xs[kk][ty * 4 + 0];
            const float a1 = xs[kk][ty * 4 + 1];
            const float a2 = xs[kk][ty * 4 + 2];
            const float a3 = xs[kk][ty * 4 + 3];
            #pragma unroll
            for (int j = 0; j < 6; j++) {
                const float b = wsT[kk][tx + j * 16];
                acc[0][j] = fmaf(a0, b, acc[0][j]);
                acc[1][j] = fmaf(a1, b, acc[1][j]);
                acc[2][j] = fmaf(a2, b, acc[2][j]);
                acc[3][j] = fmaf(a3, b, acc[3][j]);
            }
        }
        __syncthreads();
    }

    float* out = Pp + (size_t)blockIdx.y * (MM * 96);
    #pragma unroll
    for (int i = 0; i < 4; i++) {
        const int r = r0 + ty * 4 + i;
        #pragma unroll
        for (int j = 0; j < 6; j++)
            out[(size_t)r * 96 + tx + j * 16] = acc[i][j];
    }
}

// ---------------------------------------------------------------------------
// Kernel 1b: sum the 8 k-split partials, scatter to Bt | Ct | R1. (unchanged)
// ---------------------------------------------------------------------------
__global__ __launch_bounds__(256) void k_reduce96(
    const float* __restrict__ Pp, const float* __restrict__ log_A,
    float* __restrict__ Bt, float* __restrict__ Ct, float* __restrict__ R1)
{
    const int gid = blockIdx.x * 256 + threadIdx.x;   // 0..98303
    const int e0 = gid * 4;
    float4 s = *(const float4*)(Pp + e0);
    #pragma unroll
    for (int p = 1; p < KSPLIT; p++) {
        const float4 v = *(const float4*)(Pp + (size_t)p * MM * 96 + e0);
        s.x += v.x; s.y += v.y; s.z += v.z; s.w += v.w;
    }
    const int r = e0 / 96;
    const int c = e0 - r * 96;
    if (c < 16) {
        const float4 lgj = *(const float4*)(log_A + c);
        s.x *= 1.0f / (-__expf(lgj.x) + 1e-8f);
        s.y *= 1.0f / (-__expf(lgj.y) + 1e-8f);
        s.z *= 1.0f / (-__expf(lgj.z) + 1e-8f);
        s.w *= 1.0f / (-__expf(lgj.w) + 1e-8f);
        *(float4*)(Bt + (size_t)r * NN + c) = s;
    } else if (c < 32) {
        *(float4*)(Ct + (size_t)r * NN + (c - 16)) = s;
    } else {
        *(float4*)(R1 + (size_t)r * RR + (c - 32)) = s;
    }
}

// ---------------------------------------------------------------------------
// Kernel 2 v2: dt = softplus(R1 @ W_dt2^T + b_dt2).  (unchanged from round 4)
// ---------------------------------------------------------------------------
__global__ __launch_bounds__(256, 4) void k_dtproj(
    const float* __restrict__ R1, const float* __restrict__ W_dt2,
    const float* __restrict__ b_dt2, float* __restrict__ dt)
{
    __shared__ float r1s[64][68];    // 17.4 KB
    __shared__ float wsT[64][68];    // 17.4 KB  (wsT[k][d])

    const int tid = threadIdx.x;
    const int r0 = blockIdx.x * 64;
    const int d0 = blockIdx.y * 64;

    #pragma unroll
    for (int i = 0; i < 4; i++) {
        const int f = tid + i * 256;
        const int row = f >> 4;
        const int kq = (f & 15) * 4;
        *(float4*)&r1s[row][kq] = *(const float4*)(R1 + (size_t)(r0 + row) * RR + kq);
    }
    {
        const int dl = tid >> 2;
        const int kq0 = (tid & 3) * 16;
        const float* src = W_dt2 + (size_t)(d0 + dl) * RR + kq0;
        #pragma unroll
        for (int j = 0; j < 16; j += 4) {
            const float4 v = *(const float4*)(src + j);
            wsT[kq0 + j + 0][dl] = v.x;
            wsT[kq0 + j + 1][dl] = v.y;
            wsT[kq0 + j + 2][dl] = v.z;
            wsT[kq0 + j + 3][dl] = v.w;
        }
    }
    __syncthreads();

    const int cg = tid & 15;   // cols d0 + cg*4 .. +3
    const int rg = tid >> 4;   // rows r0 + rg*4 + i

    float4 acc[4];
    #pragma unroll
    for (int i = 0; i < 4; i++) acc[i] = make_float4(0.f, 0.f, 0.f, 0.f);

    #pragma unroll
    for (int k4 = 0; k4 < 16; k4++) {
        float r1a[4][4];
        #pragma unroll
        for (int i = 0; i < 4; i++) {
            const float4 v = *(const float4*)&r1s[rg * 4 + i][k4 * 4];
            r1a[i][0] = v.x; r1a[i][1] = v.y; r1a[i][2] = v.z; r1a[i][3] = v.w;
        }
        #pragma unroll
        for (int kk = 0; kk < 4; kk++) {
            const float4 w = *(const float4*)&wsT[k4 * 4 + kk][cg * 4];
            #pragma unroll
            for (int i = 0; i < 4; i++) {
                const float a = r1a[i][kk];
                acc[i].x = fmaf(a, w.x, acc[i].x);
                acc[i].y = fmaf(a, w.y, acc[i].y);
                acc[i].z = fmaf(a, w.z, acc[i].z);
                acc[i].w = fmaf(a, w.w, acc[i].w);
            }
        }
    }

    const float4 bias = *(const float4*)(b_dt2 + d0 + cg * 4);
    #pragma unroll
    for (int i = 0; i < 4; i++) {
        const int row = r0 + rg * 4 + i;
        float4 o;
        o.x = softplus_f(acc[i].x + bias.x);
        o.y = softplus_f(acc[i].y + bias.y);
        o.z = softplus_f(acc[i].z + bias.z);
        o.w = softplus_f(acc[i].w + bias.w);
        *(float4*)(dt + (size_t)row * DD + d0 + cg * 4) = o;
    }
}

// ---------------------------------------------------------------------------
// Scan v11: PREFETCH-ALL.  One thread per d-channel, 16 n-states in
// registers.  All CHUNK x/dt loads are hoisted into VGPR arrays with
// static indices (full unroll), so HBM/L2 latency is exposed ONCE per
// block (drained at the staging barrier) instead of every 4 t-steps.
// Compute loop then runs against registers with zero vmcnt stalls.
// ---------------------------------------------------------------------------
__global__ __launch_bounds__(256, 2) void k_scan1(
    const float* __restrict__ x, const float* __restrict__ dt,
    const float* __restrict__ Bt, const float* __restrict__ log_A,
    float* __restrict__ P, float* __restrict__ Sg)
{
    __shared__ float bt_s[CHUNK][NN];   // 2 KB

    const int tid = threadIdx.x;
    const int d = blockIdx.x * 256 + tid;
    const int c = blockIdx.y;
    const int b = blockIdx.z;
    const int base = b * TT + c * CHUNK;

    if (tid < CHUNK * NN / 4) {         // 128 threads stage Bt
        const int t = tid >> 2;
        const int jc = (tid & 3) * 4;
        *(float4*)&bt_s[t][jc] = *(const float4*)(Bt + (size_t)(base + t) * NN + jc);
    }

    // prefetch ALL x/dt for this thread's d-column into registers
    const float* gdt = dt + (size_t)base * DD + d;
    const float* gx  = x  + (size_t)base * DD + d;
    float dv[CHUNK], xv[CHUNK];
    #pragma unroll
    for (int t = 0; t < CHUNK; t++) {
        dv[t] = gdt[(size_t)t * DD];
        xv[t] = gx[(size_t)t * DD];
    }

    float A2[16];
    #pragma unroll
    for (int q = 0; q < 4; q++) {
        const float4 lg = *(const float4*)(log_A + d * NN + q * 4);
        A2[q * 4 + 0] = -__expf(lg.x) * LOG2E;
        A2[q * 4 + 1] = -__expf(lg.y) * LOG2E;
        A2[q * 4 + 2] = -__expf(lg.z) * LOG2E;
        A2[q * 4 + 3] = -__expf(lg.w) * LOG2E;
    }

    __syncthreads();

    float s[16];
    #pragma unroll
    for (int n = 0; n < 16; n++) s[n] = 0.0f;
    float dtsum = 0.0f;

    #pragma unroll
    for (int t = 0; t < CHUNK; t++) {
        const float dtv = dv[t];
        const float xvv = xv[t];
        dtsum += dtv;
        #pragma unroll
        for (int q = 0; q < 4; q++) {
            const float4 bt4 = *(const float4*)&bt_s[t][q * 4];
            const float a0 = EXP2(dtv * A2[q * 4 + 0]);
            const float a1 = EXP2(dtv * A2[q * 4 + 1]);
            const float a2 = EXP2(dtv * A2[q * 4 + 2]);
            const float a3 = EXP2(dtv * A2[q * 4 + 3]);
            const float u0 = xvv * bt4.x;
            const float u1 = xvv * bt4.y;
            const float u2 = xvv * bt4.z;
            const float u3 = xvv * bt4.w;
            s[q * 4 + 0] = fmaf(a0, s[q * 4 + 0] + u0, -u0);
            s[q * 4 + 1] = fmaf(a1, s[q * 4 + 1] + u1, -u1);
            s[q * 4 + 2] = fmaf(a2, s[q * 4 + 2] + u2, -u2);
            s[q * 4 + 3] = fmaf(a3, s[q * 4 + 3] + u3, -u3);
        }
    }

    const size_t o = ((size_t)(c * BB + b) * DD + d) * NN;
    #pragma unroll
    for (int q = 0; q < 4; q++) {
        *(float4*)(P + o + q * 4) = make_float4(
            EXP2(A2[q * 4 + 0] * dtsum), EXP2(A2[q * 4 + 1] * dtsum),
            EXP2(A2[q * 4 + 2] * dtsum), EXP2(A2[q * 4 + 3] * dtsum));
        *(float4*)(Sg + o + q * 4) = make_float4(
            s[q * 4 + 0], s[q * 4 + 1], s[q * 4 + 2], s[q * 4 + 3]);
    }
}

// Prefix-combine over chunks: Hinit[c] = h-state at START of chunk c. (unchanged)
__global__ __launch_bounds__(256) void k_comb(
    const float* __restrict__ P, const float* __restrict__ Sg,
    float* __restrict__ Hs)
{
    const int flat = blockIdx.x * 256 + threadIdx.x;   // 0..32767
    float h = 0.0f;
    #pragma unroll 8
    for (int c = 0; c < NCHUNK; c++) {
        const size_t idx = (size_t)c * (BB * DD * NN) + flat;
        Hs[idx] = h;
        h = fmaf(P[idx], h, Sg[idx]);
    }
}

__global__ __launch_bounds__(256, 2) void k_scan2(
    const float* __restrict__ x, const float* __restrict__ dt,
    const float* __restrict__ Bt, const float* __restrict__ Ct,
    const float* __restrict__ log_A, const float* __restrict__ D_skip,
    const float* __restrict__ Hs, float* __restrict__ y)
{
    __shared__ float bt_s[CHUNK][NN];   // 2 KB
    __shared__ float ct_s[CHUNK][NN];   // 2 KB

    const int tid = threadIdx.x;
    const int d = blockIdx.x * 256 + tid;
    const int c = blockIdx.y;
    const int b = blockIdx.z;
    const int base = b * TT + c * CHUNK;

    if (tid < 128) {                    // 128 threads stage Bt, 128 Ct
        const int t = tid >> 2;
        const int jc = (tid & 3) * 4;
        *(float4*)&bt_s[t][jc] = *(const float4*)(Bt + (size_t)(base + t) * NN + jc);
    } else {
        const int t2 = (tid - 128) >> 2;
        const int jc = (tid & 3) * 4;
        *(float4*)&ct_s[t2][jc] = *(const float4*)(Ct + (size_t)(base + t2) * NN + jc);
    }

    // prefetch ALL x/dt for this thread's d-column into registers
    const float* gdt = dt + (size_t)base * DD + d;
    const float* gx  = x  + (size_t)base * DD + d;
    float dv[CHUNK], xv[CHUNK];
    #pragma unroll
    for (int t = 0; t < CHUNK; t++) {
        dv[t] = gdt[(size_t)t * DD];
        xv[t] = gx[(size_t)t * DD];
    }

    float A2[16];
    #pragma unroll
    for (int q = 0; q < 4; q++) {
        const float4 lg = *(const float4*)(log_A + d * NN + q * 4);
        A2[q * 4 + 0] = -__expf(lg.x) * LOG2E;
        A2[q * 4 + 1] = -__expf(lg.y) * LOG2E;
        A2[q * 4 + 2] = -__expf(lg.z) * LOG2E;
        A2[q * 4 + 3] = -__expf(lg.w) * LOG2E;
    }
    const float dsk = D_skip[d];

    float h[16];
    {
        const size_t hoff = (size_t)c * (BB * DD * NN) + (size_t)b * (DD * NN) + (size_t)d * NN;
        #pragma unroll
        for (int q = 0; q < 4; q++) {
            const float4 hv = *(const float4*)(Hs + hoff + q * 4);
            h[q * 4 + 0] = hv.x; h[q * 4 + 1] = hv.y;
            h[q * 4 + 2] = hv.z; h[q * 4 + 3] = hv.w;
        }
    }

    __syncthreads();

    float* yp = y + (size_t)base * DD + d;

    #pragma unroll
    for (int t = 0; t < CHUNK; t++) {
        const float dtv = dv[t];
        const float xvv = xv[t];
        float part = 0.0f;
        #pragma unroll
        for (int q = 0; q < 4; q++) {
            const float4 bt4 = *(const float4*)&bt_s[t][q * 4];
            const float4 ct4 = *(const float4*)&ct_s[t][q * 4];
            const float a0 = EXP2(dtv * A2[q * 4 + 0]);
            const float a1 = EXP2(dtv * A2[q * 4 + 1]);
            const float a2 = EXP2(dtv * A2[q * 4 + 2]);
            const float a3 = EXP2(dtv * A2[q * 4 + 3]);
            const float u0 = xvv * bt4.x;
            const float u1 = xvv * bt4.y;
            const float u2 = xvv * bt4.z;
            const float u3 = xvv * bt4.w;
            h[q * 4 + 0] = fmaf(a0, h[q * 4 + 0] + u0, -u0);
            h[q * 4 + 1] = fmaf(a1, h[q * 4 + 1] + u1, -u1);
            h[q * 4 + 2] = fmaf(a2, h[q * 4 + 2] + u2, -u2);
            h[q * 4 + 3] = fmaf(a3, h[q * 4 + 3] + u3, -u3);
            part = fmaf(h[q * 4 + 0], ct4.x, part);
            part = fmaf(h[q * 4 + 1], ct4.y, part);
            part = fmaf(h[q * 4 + 2], ct4.z, part);
            part = fmaf(h[q * 4 + 3], ct4.w, part);
        }
        yp[(size_t)t * DD] = fmaf(dsk, xvv, part);
    }
}

// ---------------------------------------------------------------------------
extern "C" void kernel_launch(void* const* d_in, const int* in_sizes, int n_in,
                              void* d_out, int out_size, void* d_ws, size_t ws_size,
                              hipStream_t stream)
{
    const float* x      = (const float*)d_in[0];
    const float* W_B    = (const float*)d_in[1];
    const float* W_C    = (const float*)d_in[2];
    const float* W_dt1  = (const float*)d_in[3];
    const float* W_dt2  = (const float*)d_in[4];
    const float* b_dt2  = (const float*)d_in[5];
    const float* log_A  = (const float*)d_in[6];
    const float* D_skip = (const float*)d_in[7];
    float* y = (float*)d_out;

    float* ws = (float*)d_ws;
    float* Bt = ws + BT_OFF;
    float* Ct = ws + CT_OFF;
    float* R1 = ws + R1_OFF;
    float* dt = ws + DT_OFF;
    float* P  = ws + P_OFF;
    float* S  = ws + S_OFF;
    float* Hs = ws + H_OFF;
    float* Pp = ws + PP_OFF;

    k_proj96<<<dim3(MM / 64, KSPLIT), 256, 0, stream>>>(x, W_B, W_C, W_dt1, Pp);
    k_reduce96<<<dim3(MM * 96 / 4 / 256), 256, 0, stream>>>(Pp, log_A, Bt, Ct, R1);
    k_dtproj<<<dim3(MM / 64, DD / 64), 256, 0, stream>>>(R1, W_dt2, b_dt2, dt);
    k_scan1<<<dim3(DD / 256, NCHUNK, BB), 256, 0, stream>>>(x, dt, Bt, log_A, P, S);
    k_comb<<<dim3(BB * DD * NN / 256), 256, 0, stream>>>(P, S, Hs);
    k_scan2<<<dim3(DD / 256, NCHUNK, BB), 256, 0, stream>>>(x, dt, Bt, Ct, log_A, D_skip, Hs, y);
}